// Round 10
// baseline (2986.928 us; speedup 1.0000x reference)
//
#include <hip/hip_runtime.h>

#define N_      50000
#define E_      800000
#define HC_     128
#define ED_     44
#define NH_     4
#define DEGCAP_ 96   // Poisson(16); P(deg>96) astronomically small

// ---------------- x @ W[mat] + b : 32-row tile, one mat per block (grid.y)
// (r3/r6-proven version, ~183us; r9's 2-step prefetch regressed — reverted)
__global__ __launch_bounds__(256) void k_lin(
    const float* __restrict__ x,
    const float* __restrict__ Wq, const float* __restrict__ bq,
    const float* __restrict__ Wk, const float* __restrict__ bk,
    const float* __restrict__ Wv, const float* __restrict__ bv,
    const float* __restrict__ Wsk, const float* __restrict__ bsk,
    float* __restrict__ q, float* __restrict__ k, float* __restrict__ v,
    float* __restrict__ skip)
{
    __shared__ float xs[32 * 128];    // 16 KB
    const int n0 = blockIdx.x * 32;
    const int t  = threadIdx.x;

    #pragma unroll
    for (int i = 0; i < 4; ++i) {
        int idx = t + i * 256;        // float4 index, 0..1023
        int row = idx >> 5;
        float4 a = make_float4(0.f, 0.f, 0.f, 0.f);
        if (n0 + row < N_) a = ((const float4*)x)[(size_t)n0 * 32 + idx];
        *(float4*)&xs[idx * 4] = a;
    }
    __syncthreads();

    const float* Wm[4] = {Wq, Wk, Wv, Wsk};
    const float* bm[4] = {bq, bk, bv, bsk};
    float* om[4] = {q, k, v, skip};
    const int mat = blockIdx.y;
    const float* W = Wm[mat];

    const int tx = t & 31, ty = t >> 5;
    float acc[4][4];
    #pragma unroll
    for (int r = 0; r < 4; ++r) {
        acc[r][0] = 0.f; acc[r][1] = 0.f; acc[r][2] = 0.f; acc[r][3] = 0.f;
    }

    float4 wb[4];
    #pragma unroll
    for (int dd = 0; dd < 4; ++dd)
        wb[dd] = *(const float4*)(W + dd * 128 + tx * 4);

    for (int s = 0; s < 32; ++s) {
        int sn = (s + 1) & 31;
        float4 wn[4];
        #pragma unroll
        for (int dd = 0; dd < 4; ++dd)
            wn[dd] = *(const float4*)(W + (sn * 4 + dd) * 128 + tx * 4);
        #pragma unroll
        for (int r = 0; r < 4; ++r) {
            float4 xv = *(const float4*)&xs[(ty * 4 + r) * 128 + s * 4];
            acc[r][0] += xv.x * wb[0].x + xv.y * wb[1].x + xv.z * wb[2].x + xv.w * wb[3].x;
            acc[r][1] += xv.x * wb[0].y + xv.y * wb[1].y + xv.z * wb[2].y + xv.w * wb[3].y;
            acc[r][2] += xv.x * wb[0].z + xv.y * wb[1].z + xv.z * wb[2].z + xv.w * wb[3].z;
            acc[r][3] += xv.x * wb[0].w + xv.y * wb[1].w + xv.z * wb[2].w + xv.w * wb[3].w;
        }
        #pragma unroll
        for (int dd = 0; dd < 4; ++dd) wb[dd] = wn[dd];
    }

    float4 b4 = *(const float4*)(bm[mat] + tx * 4);
    float* o = om[mat];
    #pragma unroll
    for (int r = 0; r < 4; ++r) {
        int n = n0 + ty * 4 + r;
        if (n < N_) {
            float4 rr = make_float4(acc[r][0] + b4.x, acc[r][1] + b4.y,
                                    acc[r][2] + b4.z, acc[r][3] + b4.w);
            ((float4*)(o + (size_t)n * 128))[tx] = rr;
        }
    }
}

// --------------------------- padded-CSR build: one atomic pass, no scan
__global__ __launch_bounds__(256) void k_scatter(const int* __restrict__ ei,
                                                 int* __restrict__ cnt,
                                                 int2* __restrict__ csr) {
    int e = blockIdx.x * 256 + threadIdx.x;   // E_ divisible by 256
    int src = ei[e], dst = ei[E_ + e];
    int pos = atomicAdd(&cnt[dst], 1);
    if (pos < DEGCAP_) csr[(size_t)dst * DEGCAP_ + pos] = make_int2(src, e);
}

// ------------- wave-per-node, single-pass deferred normalization,
// *** ZERO LDS *** — every LDS>0 kernel in 10 rounds sat at ~2.5 blocks/CU
// (30-49% occupancy) regardless of size; the one LDS-free kernel hit 82%.
// (1) q staging -> direct broadcast global loads (L1/L3-hot rows).
// (2) qWe exchange -> each lane computes its OWN 12 qWe dims (We 22KB,
//     L1-hot; +384 FMA vs VALUBusy 19% headroom).
// (3) epilogue staging -> xor-butterfly leaves reduced sums in ALL lanes;
//     We-contraction stays in the (eh,si) layout via 44 shfl pulls; g==0
//     lanes write the output slice directly. No barriers anywhere.
__global__ __launch_bounds__(256, 4) void k_node(
    const int* __restrict__ cnt, const int2* __restrict__ csr,
    const float* __restrict__ ea, const float* __restrict__ We,
    const float* __restrict__ q, const float* __restrict__ k,
    const float* __restrict__ v, const float* __restrict__ skip,
    float* __restrict__ out)
{
    const int t = threadIdx.x, w = t >> 6, l = t & 63;
    const int n = blockIdx.x * 4 + w;
    const int g = l >> 4, ii = l & 15, eh = ii >> 2, si = ii & 3;

    const float* qrow = q + (size_t)n * HC_ + eh * 32;
    // q fragment for the alpha dot (channels si*8..+8 of head eh)
    const float4 qa = *(const float4*)(qrow + si * 8);
    const float4 qb = *(const float4*)(qrow + si * 8 + 4);

    // ---- qWe: lane computes its own 12 dims (si*12..+11) of head eh.
    float4 w0, w1, w2;
    {
        float4 q4[8];
        #pragma unroll
        for (int i = 0; i < 8; ++i) q4[i] = *(const float4*)(qrow + i * 4);
        float qw[12];
        const int db = si * 12;
        #pragma unroll
        for (int j = 0; j < 12; ++j) {
            int d  = db + j;
            int dr = d < ED_ ? d : ED_ - 1;    // clamp (si==3, j>=8)
            const float* wr = We + dr * HC_ + eh * 32;
            float acc = 0.f;
            #pragma unroll
            for (int i = 0; i < 8; ++i) {
                float4 a = *(const float4*)(wr + i * 4);
                acc += q4[i].x*a.x + q4[i].y*a.y + q4[i].z*a.z + q4[i].w*a.w;
            }
            qw[j] = acc;
        }
        w0 = make_float4(qw[0], qw[1], qw[2],  qw[3]);
        w1 = make_float4(qw[4], qw[5], qw[6],  qw[7]);
        w2 = (si < 3) ? make_float4(qw[8], qw[9], qw[10], qw[11])
                      : make_float4(0.f, 0.f, 0.f, 0.f);
    }
    const int eoff2 = (si < 3) ? si * 12 + 8 : 36;

    int deg = cnt[n];
    deg = deg < DEGCAP_ ? deg : DEGCAP_;
    const int2* crow = csr + (size_t)n * DEGCAP_;
    int2 c0 = make_int2(0, 0);
    if (deg > 0) c0 = crow[l < deg ? l : deg - 1];

    float4 av0 = make_float4(0.f,0.f,0.f,0.f), av1 = make_float4(0.f,0.f,0.f,0.f);
    float4 aeA = make_float4(0.f,0.f,0.f,0.f), aeB = make_float4(0.f,0.f,0.f,0.f);
    float4 aeC = make_float4(0.f,0.f,0.f,0.f);
    float ssum = 0.f;

    const int lim = deg < 64 ? deg : 64;
    for (int base = 0; base < lim; base += 8) {
        const int slotA = base + g,     slotB = base + 4 + g;
        const int scA = slotA < lim ? slotA : lim - 1;
        const int scB = slotB < lim ? slotB : lim - 1;
        const int sA = __shfl(c0.x, scA), eEA = __shfl(c0.y, scA);
        const int sB = __shfl(c0.x, scB), eEB = __shfl(c0.y, scB);

        // ---------- load block: 14 independent float4 gathers
        const float* kpA = k + (size_t)sA * HC_ + eh * 32 + si * 8;
        const float* vpA = v + (size_t)sA * HC_ + eh * 32 + si * 8;
        const float* epA = ea + (size_t)eEA * ED_;
        const float* kpB = k + (size_t)sB * HC_ + eh * 32 + si * 8;
        const float* vpB = v + (size_t)sB * HC_ + eh * 32 + si * 8;
        const float* epB = ea + (size_t)eEB * ED_;
        const float4 kaA = *(const float4*)kpA;
        const float4 kbA = *(const float4*)(kpA + 4);
        const float4 vaA = *(const float4*)vpA;
        const float4 vbA = *(const float4*)(vpA + 4);
        const float4 e0A = *(const float4*)(epA + si * 12);
        const float4 e1A = *(const float4*)(epA + si * 12 + 4);
        const float4 e2A = *(const float4*)(epA + eoff2);
        const float4 kaB = *(const float4*)kpB;
        const float4 kbB = *(const float4*)(kpB + 4);
        const float4 vaB = *(const float4*)vpB;
        const float4 vbB = *(const float4*)(vpB + 4);
        const float4 e0B = *(const float4*)(epB + si * 12);
        const float4 e1B = *(const float4*)(epB + si * 12 + 4);
        const float4 e2B = *(const float4*)(epB + eoff2);

        float pA = qa.x*kaA.x + qa.y*kaA.y + qa.z*kaA.z + qa.w*kaA.w
                 + qb.x*kbA.x + qb.y*kbA.y + qb.z*kbA.z + qb.w*kbA.w
                 + w0.x*e0A.x + w0.y*e0A.y + w0.z*e0A.z + w0.w*e0A.w
                 + w1.x*e1A.x + w1.y*e1A.y + w1.z*e1A.z + w1.w*e1A.w
                 + w2.x*e2A.x + w2.y*e2A.y + w2.z*e2A.z + w2.w*e2A.w;
        float pB = qa.x*kaB.x + qa.y*kaB.y + qa.z*kaB.z + qa.w*kaB.w
                 + qb.x*kbB.x + qb.y*kbB.y + qb.z*kbB.z + qb.w*kbB.w
                 + w0.x*e0B.x + w0.y*e0B.y + w0.z*e0B.z + w0.w*e0B.w
                 + w1.x*e1B.x + w1.y*e1B.y + w1.z*e1B.z + w1.w*e1B.w
                 + w2.x*e2B.x + w2.y*e2B.y + w2.z*e2B.z + w2.w*e2B.w;
        pA += __shfl_xor(pA, 1);  pB += __shfl_xor(pB, 1);
        pA += __shfl_xor(pA, 2);  pB += __shfl_xor(pB, 2);
        const float alA = fminf(pA * 0.17677669529663687f, 40.f);
        const float alB = fminf(pB * 0.17677669529663687f, 40.f);
        const float wjA = (slotA < lim) ? __expf(alA) : 0.f;
        const float wjB = (slotB < lim) ? __expf(alB) : 0.f;

        ssum  += wjA + wjB;
        av0.x += wjA * vaA.x + wjB * vaB.x;  av0.y += wjA * vaA.y + wjB * vaB.y;
        av0.z += wjA * vaA.z + wjB * vaB.z;  av0.w += wjA * vaA.w + wjB * vaB.w;
        av1.x += wjA * vbA.x + wjB * vbB.x;  av1.y += wjA * vbA.y + wjB * vbB.y;
        av1.z += wjA * vbA.z + wjB * vbB.z;  av1.w += wjA * vbA.w + wjB * vbB.w;
        aeA.x += wjA * e0A.x + wjB * e0B.x;  aeA.y += wjA * e0A.y + wjB * e0B.y;
        aeA.z += wjA * e0A.z + wjB * e0B.z;  aeA.w += wjA * e0A.w + wjB * e0B.w;
        aeB.x += wjA * e1A.x + wjB * e1B.x;  aeB.y += wjA * e1A.y + wjB * e1B.y;
        aeB.z += wjA * e1A.z + wjB * e1B.z;  aeB.w += wjA * e1A.w + wjB * e1B.w;
        aeC.x += wjA * e2A.x + wjB * e2B.x;  aeC.y += wjA * e2A.y + wjB * e2B.y;
        aeC.z += wjA * e2A.z + wjB * e2B.z;  aeC.w += wjA * e2A.w + wjB * e2B.w;
    }

    // ---- rare deg>64 tail: wave-uniform single-edge steps
    for (int j = 64; j < deg; ++j) {
        int2 se = crow[j];
        int sA = __builtin_amdgcn_readfirstlane(se.x);
        int eA = __builtin_amdgcn_readfirstlane(se.y);
        const float* kp = k + (size_t)sA * HC_ + eh * 32 + si * 8;
        const float* vp = v + (size_t)sA * HC_ + eh * 32 + si * 8;
        const float* ep = ea + (size_t)eA * ED_;
        float4 ka = *(const float4*)kp, kb = *(const float4*)(kp + 4);
        float4 va = *(const float4*)vp, vb = *(const float4*)(vp + 4);
        float4 e0 = *(const float4*)(ep + si * 12);
        float4 e1 = *(const float4*)(ep + si * 12 + 4);
        float4 e2 = *(const float4*)(ep + eoff2);
        float p = qa.x*ka.x + qa.y*ka.y + qa.z*ka.z + qa.w*ka.w
                + qb.x*kb.x + qb.y*kb.y + qb.z*kb.z + qb.w*kb.w
                + w0.x*e0.x + w0.y*e0.y + w0.z*e0.z + w0.w*e0.w
                + w1.x*e1.x + w1.y*e1.y + w1.z*e1.z + w1.w*e1.w
                + w2.x*e2.x + w2.y*e2.y + w2.z*e2.z + w2.w*e2.w;
        p += __shfl_xor(p, 1);
        p += __shfl_xor(p, 2);
        float wj = (g == 0) ? __expf(fminf(p * 0.17677669529663687f, 40.f)) : 0.f;
        ssum  += wj;
        av0.x += wj * va.x; av0.y += wj * va.y; av0.z += wj * va.z; av0.w += wj * va.w;
        av1.x += wj * vb.x; av1.y += wj * vb.y; av1.z += wj * vb.z; av1.w += wj * vb.w;
        aeA.x += wj * e0.x; aeA.y += wj * e0.y; aeA.z += wj * e0.z; aeA.w += wj * e0.w;
        aeB.x += wj * e1.x; aeB.y += wj * e1.y; aeB.z += wj * e1.z; aeB.w += wj * e1.w;
        aeC.x += wj * e2.x; aeC.y += wj * e2.y; aeC.z += wj * e2.z; aeC.w += wj * e2.w;
    }

    // ---- cross-group reduction over g (xor 16, 32): ALL lanes get the sums
    #pragma unroll
    for (int d = 16; d <= 32; d <<= 1) {
        ssum  += __shfl_xor(ssum,  d);
        av0.x += __shfl_xor(av0.x, d); av0.y += __shfl_xor(av0.y, d);
        av0.z += __shfl_xor(av0.z, d); av0.w += __shfl_xor(av0.w, d);
        av1.x += __shfl_xor(av1.x, d); av1.y += __shfl_xor(av1.y, d);
        av1.z += __shfl_xor(av1.z, d); av1.w += __shfl_xor(av1.w, d);
        aeA.x += __shfl_xor(aeA.x, d); aeA.y += __shfl_xor(aeA.y, d);
        aeA.z += __shfl_xor(aeA.z, d); aeA.w += __shfl_xor(aeA.w, d);
        aeB.x += __shfl_xor(aeB.x, d); aeB.y += __shfl_xor(aeB.y, d);
        aeB.z += __shfl_xor(aeB.z, d); aeB.w += __shfl_xor(aeB.w, d);
        aeC.x += __shfl_xor(aeC.x, d); aeC.y += __shfl_xor(aeC.y, d);
        aeC.z += __shfl_xor(aeC.z, d); aeC.w += __shfl_xor(aeC.w, d);
    }

    // ---- We contraction in (eh,si) layout: pull each si-group's 12 ae dims
    // via shfl, FMA against We rows over my 8 channels. s==3 has 8 dims
    // (aeC there is the weighted duplicate -> never read).
    float4 ev0 = make_float4(0.f,0.f,0.f,0.f), ev1 = make_float4(0.f,0.f,0.f,0.f);
    const int lbase = l & ~3;
    #pragma unroll
    for (int s = 0; s < 4; ++s) {
        const int srcl = lbase | s;
        float pa0 = __shfl(aeA.x, srcl), pa1 = __shfl(aeA.y, srcl);
        float pa2 = __shfl(aeA.z, srcl), pa3 = __shfl(aeA.w, srcl);
        float pa4 = __shfl(aeB.x, srcl), pa5 = __shfl(aeB.y, srcl);
        float pa6 = __shfl(aeB.z, srcl), pa7 = __shfl(aeB.w, srcl);
        const float* wr = We + (s * 12) * HC_ + eh * 32 + si * 8;
        {
            float4 wa, wbv;
            wa = *(const float4*)(wr + 0 * HC_); wbv = *(const float4*)(wr + 0 * HC_ + 4);
            ev0.x += pa0*wa.x; ev0.y += pa0*wa.y; ev0.z += pa0*wa.z; ev0.w += pa0*wa.w;
            ev1.x += pa0*wbv.x; ev1.y += pa0*wbv.y; ev1.z += pa0*wbv.z; ev1.w += pa0*wbv.w;
            wa = *(const float4*)(wr + 1 * HC_); wbv = *(const float4*)(wr + 1 * HC_ + 4);
            ev0.x += pa1*wa.x; ev0.y += pa1*wa.y; ev0.z += pa1*wa.z; ev0.w += pa1*wa.w;
            ev1.x += pa1*wbv.x; ev1.y += pa1*wbv.y; ev1.z += pa1*wbv.z; ev1.w += pa1*wbv.w;
            wa = *(const float4*)(wr + 2 * HC_); wbv = *(const float4*)(wr + 2 * HC_ + 4);
            ev0.x += pa2*wa.x; ev0.y += pa2*wa.y; ev0.z += pa2*wa.z; ev0.w += pa2*wa.w;
            ev1.x += pa2*wbv.x; ev1.y += pa2*wbv.y; ev1.z += pa2*wbv.z; ev1.w += pa2*wbv.w;
            wa = *(const float4*)(wr + 3 * HC_); wbv = *(const float4*)(wr + 3 * HC_ + 4);
            ev0.x += pa3*wa.x; ev0.y += pa3*wa.y; ev0.z += pa3*wa.z; ev0.w += pa3*wa.w;
            ev1.x += pa3*wbv.x; ev1.y += pa3*wbv.y; ev1.z += pa3*wbv.z; ev1.w += pa3*wbv.w;
            wa = *(const float4*)(wr + 4 * HC_); wbv = *(const float4*)(wr + 4 * HC_ + 4);
            ev0.x += pa4*wa.x; ev0.y += pa4*wa.y; ev0.z += pa4*wa.z; ev0.w += pa4*wa.w;
            ev1.x += pa4*wbv.x; ev1.y += pa4*wbv.y; ev1.z += pa4*wbv.z; ev1.w += pa4*wbv.w;
            wa = *(const float4*)(wr + 5 * HC_); wbv = *(const float4*)(wr + 5 * HC_ + 4);
            ev0.x += pa5*wa.x; ev0.y += pa5*wa.y; ev0.z += pa5*wa.z; ev0.w += pa5*wa.w;
            ev1.x += pa5*wbv.x; ev1.y += pa5*wbv.y; ev1.z += pa5*wbv.z; ev1.w += pa5*wbv.w;
            wa = *(const float4*)(wr + 6 * HC_); wbv = *(const float4*)(wr + 6 * HC_ + 4);
            ev0.x += pa6*wa.x; ev0.y += pa6*wa.y; ev0.z += pa6*wa.z; ev0.w += pa6*wa.w;
            ev1.x += pa6*wbv.x; ev1.y += pa6*wbv.y; ev1.z += pa6*wbv.z; ev1.w += pa6*wbv.w;
            wa = *(const float4*)(wr + 7 * HC_); wbv = *(const float4*)(wr + 7 * HC_ + 4);
            ev0.x += pa7*wa.x; ev0.y += pa7*wa.y; ev0.z += pa7*wa.z; ev0.w += pa7*wa.w;
            ev1.x += pa7*wbv.x; ev1.y += pa7*wbv.y; ev1.z += pa7*wbv.z; ev1.w += pa7*wbv.w;
        }
        if (s < 3) {
            float pa8  = __shfl(aeC.x, srcl), pa9  = __shfl(aeC.y, srcl);
            float pa10 = __shfl(aeC.z, srcl), pa11 = __shfl(aeC.w, srcl);
            float4 wa, wbv;
            wa = *(const float4*)(wr + 8 * HC_); wbv = *(const float4*)(wr + 8 * HC_ + 4);
            ev0.x += pa8*wa.x; ev0.y += pa8*wa.y; ev0.z += pa8*wa.z; ev0.w += pa8*wa.w;
            ev1.x += pa8*wbv.x; ev1.y += pa8*wbv.y; ev1.z += pa8*wbv.z; ev1.w += pa8*wbv.w;
            wa = *(const float4*)(wr + 9 * HC_); wbv = *(const float4*)(wr + 9 * HC_ + 4);
            ev0.x += pa9*wa.x; ev0.y += pa9*wa.y; ev0.z += pa9*wa.z; ev0.w += pa9*wa.w;
            ev1.x += pa9*wbv.x; ev1.y += pa9*wbv.y; ev1.z += pa9*wbv.z; ev1.w += pa9*wbv.w;
            wa = *(const float4*)(wr + 10 * HC_); wbv = *(const float4*)(wr + 10 * HC_ + 4);
            ev0.x += pa10*wa.x; ev0.y += pa10*wa.y; ev0.z += pa10*wa.z; ev0.w += pa10*wa.w;
            ev1.x += pa10*wbv.x; ev1.y += pa10*wbv.y; ev1.z += pa10*wbv.z; ev1.w += pa10*wbv.w;
            wa = *(const float4*)(wr + 11 * HC_); wbv = *(const float4*)(wr + 11 * HC_ + 4);
            ev0.x += pa11*wa.x; ev0.y += pa11*wa.y; ev0.z += pa11*wa.z; ev0.w += pa11*wa.w;
            ev1.x += pa11*wbv.x; ev1.y += pa11*wbv.y; ev1.z += pa11*wbv.z; ev1.w += pa11*wbv.w;
        }
    }

    // ---- write: g==0 lanes own the (eh,si) 8-channel slice
    if (g == 0) {
        const float* skp = skip + (size_t)n * HC_ + eh * 32 + si * 8;
        const float4 s0 = *(const float4*)skp;
        const float4 s1 = *(const float4*)(skp + 4);
        const float inv = 1.0f / (ssum + 1e-16f);
        float* op = out + (size_t)n * HC_ + eh * 32 + si * 8;
        *(float4*)op = make_float4((av0.x + ev0.x) * inv + s0.x,
                                   (av0.y + ev0.y) * inv + s0.y,
                                   (av0.z + ev0.z) * inv + s0.z,
                                   (av0.w + ev0.w) * inv + s0.w);
        *(float4*)(op + 4) = make_float4((av1.x + ev1.x) * inv + s1.x,
                                         (av1.y + ev1.y) * inv + s1.y,
                                         (av1.z + ev1.z) * inv + s1.z,
                                         (av1.w + ev1.w) * inv + s1.w);
    }
}

extern "C" void kernel_launch(void* const* d_in, const int* in_sizes, int n_in,
                              void* d_out, int out_size, void* d_ws, size_t ws_size,
                              hipStream_t stream)
{
    const float* x   = (const float*)d_in[0];
    const int*   ei  = (const int*)d_in[1];
    const float* ea  = (const float*)d_in[2];
    const float* Wq  = (const float*)d_in[3];
    const float* bq  = (const float*)d_in[4];
    const float* Wk  = (const float*)d_in[5];
    const float* bk  = (const float*)d_in[6];
    const float* Wv  = (const float*)d_in[7];
    const float* bv  = (const float*)d_in[8];
    const float* We  = (const float*)d_in[9];
    const float* Wsk = (const float*)d_in[10];
    const float* bsk = (const float*)d_in[11];
    float* out = (float*)d_out;

    float* ws    = (float*)d_ws;
    float* q     = ws;                             // N*128
    float* k     = q     + (size_t)N_ * HC_;       // N*128
    float* v     = k     + (size_t)N_ * HC_;       // N*128
    float* skip  = v     + (size_t)N_ * HC_;       // N*128
    int*   cnt   = (int*)(skip + (size_t)N_ * HC_); // N
    int2*  csr   = (int2*)(cnt + N_);              // N*DEGCAP

    hipMemsetAsync(cnt, 0, N_ * sizeof(int), stream);
    k_lin    <<<dim3((N_ + 31) / 32, 4), 256, 0, stream>>>(
        x, Wq, bq, Wk, bk, Wv, bv, Wsk, bsk, q, k, v, skip);
    k_scatter<<<E_ / 256, 256, 0, stream>>>(ei, cnt, csr);
    k_node   <<<N_ / 4, 256, 0, stream>>>(cnt, csr, ea, We, q, k, v,
                                          skip, out);
}